// Round 5
// baseline (128.076 us; speedup 1.0000x reference)
//
#include <hip/hip_runtime.h>
#include <hip/hip_fp16.h>
#include <math.h>
#include <string.h>

#define Dd 192
#define Hh 192
#define Ww 192
#define K  11
#define R  5

#define TW 32            // tile width (output cols)
#define TH 16            // tile height (output rows)
#define DC 12            // output planes per chunk (22 input planes)
#define NT 128           // threads per block (2 waves)
#define NQ 8             // quads (4-col groups) per row = TW/4
#define HH_ 26           // halo rows = TH + 2R
#define SP 22            // stg row stride in dwords (22 pairs = 44 staged cols)
#define CS 16            // cwl row stride in dwords (8 quads * 2)
#define NSTG (HH_ * 11)  // 286 staging tasks (each covers 4 cols = 2 pairs)
#define NCW  (HH_ * NQ)  // 208 conv-W tasks

struct GW { unsigned int g2[K]; };   // half2(g,g) bit patterns

static __device__ __forceinline__ __half2 u2h2(unsigned int u) {
    union { unsigned int u; __half2 h; } x; x.u = u; return x.h;
}
static __device__ __forceinline__ unsigned int h22u(__half2 h) {
    union { __half2 h; unsigned int u; } x; x.h = h; return x.u;
}
static __device__ __forceinline__ unsigned int pk(float a, float b) {
    typedef __fp16 f16x2 __attribute__((ext_vector_type(2)));
    f16x2 r = __builtin_amdgcn_cvt_pkrtz(a, b);
    union { f16x2 v; unsigned int u; } x; x.v = r; return x.u;
}

__global__ __launch_bounds__(NT, 2) void fused_ssim(
    const float* __restrict__ gr, const float* __restrict__ gt,
    GW gw, double* __restrict__ acc)
{
    __shared__ __align__(16) unsigned int stg[2][HH_][SP];  // x,y fp16 pairs
    __shared__ __align__(16) unsigned int cwl[5][HH_][CS];  // conv-W out, 5 fields
    __shared__ float wsum[2];

    const int tid = threadIdx.x;
    const int q   = tid & (NQ - 1);   // quad 0..7
    const int th  = tid >> 3;         // output row 0..15
    const int w0  = blockIdx.x * TW;
    const int h0  = blockIdx.y * TH;
    const int d0  = blockIdx.z * DC;

    // ---- precompute staging geometry: <=3 tasks/thread, clamped addresses ----
    int  saddr[3][4];
    bool sok[3][4];
    int  spair[3], srow[3];
    bool sact[3];
#pragma unroll
    for (int k = 0; k < 3; ++k) {
        const int t = tid + k * NT;
        sact[k] = (t < NSTG);
        const int r  = sact[k] ? (t / 11) : 0;
        const int cc = sact[k] ? (t % 11) : 0;
        srow[k]  = r;
        spair[k] = 2 * cc;
        const int gh   = h0 - R + r;
        const bool rok = sact[k] && (gh >= 0) && (gh < Hh);
        const int ghc  = gh < 0 ? 0 : (gh >= Hh ? Hh - 1 : gh);
#pragma unroll
        for (int i = 0; i < 4; ++i) {
            const int gx   = w0 - 6 + 4 * cc + i;
            const bool cok = (gx >= 0) && (gx < Ww);
            const int gxc  = gx < 0 ? 0 : (gx >= Ww ? Ww - 1 : gx);
            saddr[k][i] = ghc * Ww + gxc;
            sok[k][i]   = rok && cok;
        }
    }

    float px[3][4], py[3][4];

    // ---- prologue: load plane iz=0 ----
    {
        const int z = d0 - R;
        const bool zok = (z >= 0);
        const int zb = (zok ? z : 0) * Hh * Ww;
#pragma unroll
        for (int k = 0; k < 3; ++k)
#pragma unroll
            for (int i = 0; i < 4; ++i) {
                const float vx = gr[zb + saddr[k][i]];
                const float vy = gt[zb + saddr[k][i]];
                const bool ok = sok[k][i] && zok;
                px[k][i] = ok ? vx : -1.0f;   // (v+1)/2 -> 0 for OOB
                py[k][i] = ok ? vy : -1.0f;
            }
    }

    unsigned int hist[K][5][2];   // conv-D ring: 11 planes x 5 fields x 4 cols
#pragma unroll
    for (int t = 0; t < K; ++t)
#pragma unroll
        for (int f = 0; f < 5; ++f) { hist[t][f][0] = 0u; hist[t][f][1] = 0u; }

    float ssim_acc = 0.0f;

    for (int c = 0; c < 2; ++c) {
#pragma unroll
        for (int j = 0; j < K; ++j) {
            const int iz = c * K + j;

            // (A) staged regs -> LDS (rescale + fp16 pack), b64 writes
#pragma unroll
            for (int k = 0; k < 3; ++k) if (sact[k]) {
                uint2 vx, vy;
                vx.x = pk(fmaf(px[k][0], 0.5f, 0.5f), fmaf(px[k][1], 0.5f, 0.5f));
                vx.y = pk(fmaf(px[k][2], 0.5f, 0.5f), fmaf(px[k][3], 0.5f, 0.5f));
                vy.x = pk(fmaf(py[k][0], 0.5f, 0.5f), fmaf(py[k][1], 0.5f, 0.5f));
                vy.y = pk(fmaf(py[k][2], 0.5f, 0.5f), fmaf(py[k][3], 0.5f, 0.5f));
                *(uint2*)&stg[0][srow[k]][spair[k]] = vx;
                *(uint2*)&stg[1][srow[k]][spair[k]] = vy;
            }
            __syncthreads();

            // (C) prefetch next plane's globals (consumed next iteration)
            if (iz < DC + 2 * R - 1) {
                const int z = d0 - R + iz + 1;
                const bool zok = (z >= 0) && (z < Dd);
                const int zb = (zok ? z : 0) * Hh * Ww;
#pragma unroll
                for (int k = 0; k < 3; ++k)
#pragma unroll
                    for (int i = 0; i < 4; ++i) {
                        const float vx = gr[zb + saddr[k][i]];
                        const float vy = gt[zb + saddr[k][i]];
                        const bool ok = sok[k][i] && zok;
                        px[k][i] = ok ? vx : -1.0f;
                        py[k][i] = ok ? vy : -1.0f;
                    }
            }

            // (D) conv-W: on-the-fly products, b64 reads/writes
#pragma unroll
            for (int k2 = 0; k2 < 2; ++k2) {
                const int t = tid + k2 * NT;
                if (t < NCW) {
                    const int r  = t >> 3;
                    const int qq = t & (NQ - 1);
                    unsigned int dx[8], dy[8];
#pragma unroll
                    for (int u = 0; u < 4; ++u) {
                        const uint2 vx = *(const uint2*)&stg[0][r][2 * qq + 2 * u];
                        const uint2 vy = *(const uint2*)&stg[1][r][2 * qq + 2 * u];
                        dx[2 * u] = vx.x; dx[2 * u + 1] = vx.y;
                        dy[2 * u] = vy.x; dy[2 * u + 1] = vy.y;
                    }
                    __half2 aA[5], aB[5];
#pragma unroll
                    for (int f = 0; f < 5; ++f) { aA[f] = u2h2(0u); aB[f] = u2h2(0u); }
#pragma unroll
                    for (int t5 = 0; t5 < K; ++t5) {
                        const int b = t5 + 1;      // starting half index
                        unsigned int xa, xb, ya, yb;
                        if ((b & 1) == 0) {
                            xa = dx[b >> 1]; xb = dx[(b >> 1) + 1];
                            ya = dy[b >> 1]; yb = dy[(b >> 1) + 1];
                        } else {
                            xa = __builtin_amdgcn_alignbit(dx[(b + 1) >> 1], dx[b >> 1], 16);
                            xb = __builtin_amdgcn_alignbit(dx[(b + 3) >> 1], dx[(b + 1) >> 1], 16);
                            ya = __builtin_amdgcn_alignbit(dy[(b + 1) >> 1], dy[b >> 1], 16);
                            yb = __builtin_amdgcn_alignbit(dy[(b + 3) >> 1], dy[(b + 1) >> 1], 16);
                        }
                        const __half2 g   = u2h2(gw.g2[t5]);
                        const __half2 hxa = u2h2(xa), hxb = u2h2(xb);
                        const __half2 hya = u2h2(ya), hyb = u2h2(yb);
                        aA[0] = __hfma2(g, hxa, aA[0]);  aB[0] = __hfma2(g, hxb, aB[0]);
                        aA[1] = __hfma2(g, hya, aA[1]);  aB[1] = __hfma2(g, hyb, aB[1]);
                        aA[2] = __hfma2(g, __hmul2(hxa, hxa), aA[2]);
                        aB[2] = __hfma2(g, __hmul2(hxb, hxb), aB[2]);
                        aA[3] = __hfma2(g, __hmul2(hya, hya), aA[3]);
                        aB[3] = __hfma2(g, __hmul2(hyb, hyb), aB[3]);
                        aA[4] = __hfma2(g, __hmul2(hxa, hya), aA[4]);
                        aB[4] = __hfma2(g, __hmul2(hxb, hyb), aB[4]);
                    }
#pragma unroll
                    for (int f = 0; f < 5; ++f) {
                        uint2 o; o.x = h22u(aA[f]); o.y = h22u(aB[f]);
                        *(uint2*)&cwl[f][r][2 * qq] = o;
                    }
                }
            }
            __syncthreads();

            // (F) conv-H: 55 conflict-free b64 reads
            __half2 cA[5], cB[5];
#pragma unroll
            for (int f = 0; f < 5; ++f) { cA[f] = u2h2(0u); cB[f] = u2h2(0u); }
#pragma unroll
            for (int t6 = 0; t6 < K; ++t6) {
                const __half2 g = u2h2(gw.g2[t6]);
#pragma unroll
                for (int f = 0; f < 5; ++f) {
                    const uint2 v = *(const uint2*)&cwl[f][th + t6][2 * q];
                    cA[f] = __hfma2(g, u2h2(v.x), cA[f]);
                    cB[f] = __hfma2(g, u2h2(v.y), cB[f]);
                }
            }
#pragma unroll
            for (int f = 0; f < 5; ++f) {
                hist[j][f][0] = h22u(cA[f]);
                hist[j][f][1] = h22u(cB[f]);
            }

            // conv-D + SSIM once the ring is full
            if (iz >= 2 * R) {
                __half2 sA[5], sB[5];
#pragma unroll
                for (int f = 0; f < 5; ++f) { sA[f] = u2h2(0u); sB[f] = u2h2(0u); }
#pragma unroll
                for (int t7 = 0; t7 < K; ++t7) {
                    const int s = (j + 1 + t7) % K;   // static after unroll
                    const __half2 g = u2h2(gw.g2[t7]);
#pragma unroll
                    for (int f = 0; f < 5; ++f) {
                        sA[f] = __hfma2(g, u2h2(hist[s][f][0]), sA[f]);
                        sB[f] = __hfma2(g, u2h2(hist[s][f][1]), sB[f]);
                    }
                }
                const float C1 = 1e-4f, C2 = 9e-4f;
#pragma unroll
                for (int hv = 0; hv < 2; ++hv) {
                    const __half2 v0 = hv ? sB[0] : sA[0];
                    const __half2 v1 = hv ? sB[1] : sA[1];
                    const __half2 v2 = hv ? sB[2] : sA[2];
                    const __half2 v3 = hv ? sB[3] : sA[3];
                    const __half2 v4 = hv ? sB[4] : sA[4];
#pragma unroll
                    for (int col = 0; col < 2; ++col) {
                        const float m1  = col ? __high2float(v0) : __low2float(v0);
                        const float m2  = col ? __high2float(v1) : __low2float(v1);
                        const float e11 = col ? __high2float(v2) : __low2float(v2);
                        const float e22 = col ? __high2float(v3) : __low2float(v3);
                        const float e12 = col ? __high2float(v4) : __low2float(v4);
                        const float mu1sq = m1 * m1, mu2sq = m2 * m2, mu12 = m1 * m2;
                        const float s11 = e11 - mu1sq;
                        const float s22 = e22 - mu2sq;
                        const float s12 = e12 - mu12;
                        const float num = (2.f * mu12 + C1) * (2.f * s12 + C2);
                        const float den = (mu1sq + mu2sq + C1) * (s11 + s22 + C2);
                        ssim_acc += num * __builtin_amdgcn_rcpf(den);
                    }
                }
            }
        }
    }

    // ---- block reduction + one atomic ----
    float v = ssim_acc;
#pragma unroll
    for (int o = 32; o > 0; o >>= 1) v += __shfl_down(v, o);
    const int lane = tid & 63;
    const int wid  = tid >> 6;
    if (lane == 0) wsum[wid] = v;
    __syncthreads();
    if (tid == 0) atomicAdd(acc, (double)(wsum[0] + wsum[1]));
}

__global__ void k4_final(const double* __restrict__ acc, float* __restrict__ out) {
    if (threadIdx.x == 0) {
        const double n = (double)((size_t)Dd * Hh * Ww);
        out[0] = (float)(1.0 - (*acc) / n);
    }
}

// host-side float -> half (RNE)
static unsigned short f2h(float x) {
    unsigned int u; memcpy(&u, &x, 4);
    unsigned int s = (u >> 16) & 0x8000u;
    int e = (int)((u >> 23) & 0xffu) - 112;
    unsigned int m = u & 0x7fffffu;
    if (e <= 0) return (unsigned short)s;
    unsigned int mant = m + 0xFFFu + ((m >> 13) & 1u);
    if (mant & 0x800000u) { mant = 0; e += 1; }
    return (unsigned short)(s | ((unsigned)e << 10) | (mant >> 13));
}

extern "C" void kernel_launch(void* const* d_in, const int* in_sizes, int n_in,
                              void* d_out, int out_size, void* d_ws, size_t ws_size,
                              hipStream_t stream) {
    const float* gr = (const float*)d_in[0];
    const float* gt = (const float*)d_in[1];
    float* out = (float*)d_out;

    // 1D normalized gaussian (exact outer-product factorization of the 3D window)
    GW gw;
    {
        double e[K], s = 0.0;
        for (int i = 0; i < K; ++i) {
            const double a = (double)((i - R) * (i - R));
            e[i] = exp(-a / (2.0 * 1.5 * 1.5));
            s += e[i];
        }
        for (int i = 0; i < K; ++i) {
            unsigned short h = f2h((float)(e[i] / s));
            gw.g2[i] = (unsigned int)h | ((unsigned int)h << 16);
        }
    }

    double* acc = (double*)d_ws;
    (void)hipMemsetAsync(d_ws, 0, sizeof(double), stream);

    dim3 grid(Ww / TW, Hh / TH, Dd / DC);   // 6 x 12 x 16 = 1152 blocks
    fused_ssim<<<grid, NT, 0, stream>>>(gr, gt, gw, acc);

    k4_final<<<1, 64, 0, stream>>>(acc, out);
}